// Round 6
// baseline (332.492 us; speedup 1.0000x reference)
//
#include <hip/hip_runtime.h>
#include <hip/hip_bf16.h>
#include <cstdint>

// B=256, I=H=O=4096 single-step Elman RNN + linear + softmax.
// out[0..1048576) = probs (fp32), out[1048576..2097152) = hn (fp32).
//
// R6: request-volume fix. Empirical law from R1/R2/R4/R5: dur ≈ total
// global-load-request bytes / ~7 TB/s (request-rate bound, not HBM/LDS/MFMA).
//  - BM=256 (full M): W panels requested exactly ONCE (was x2).
//  - BN=256: A-redundancy 32 -> 16. MODE0 requests 512 -> 256 MB.
//  - 1024 thr = 16 waves (4x4 of 64x64), acc 64 f32/lane, BK=64,
//    static LDS 128 KB (2 x 64 KB bf16 double-buffer).
//  - Single staging reg-set, issue 2 steps ahead (T14 issue-early/
//    write-late; per-wave vmcnt(0) sits after a full compute phase).
//  - 16 K-slices x 16 ntiles... grid = 16 ntiles * 16 ks = 256 blocks.

using short8 = __attribute__((ext_vector_type(8))) short;
using f32x4  = __attribute__((ext_vector_type(4))) float;

#define HDIM 4096

__device__ __forceinline__ short bfbits(float f) {
    __bf16 b = (__bf16)f;
    return __builtin_bit_cast(short, b);
}
__device__ __forceinline__ short8 pack8(const float4& a, const float4& b) {
    short8 r;
    r[0] = bfbits(a.x); r[1] = bfbits(a.y); r[2] = bfbits(a.z); r[3] = bfbits(a.w);
    r[4] = bfbits(b.x); r[5] = bfbits(b.y); r[6] = bfbits(b.z); r[7] = bfbits(b.w);
    return r;
}

// One K-slice partial of out += A[256 x K] @ W[256 rows]^T, atomicAdd'ed.
// MODE 0: ks 0..7 -> (A0,W0) slice ks; ks 8..15 -> (A1,W1) slice ks-8.
// MODE 1: ks 0..15 -> contiguous K slices.
// Block: 1024 thr = 16 waves (4M x 4N), wave-tile 64x64. BK=64 bf16 LDS.
template<int MODE>
__global__ __launch_bounds__(1024) void rnn_gemm(
    const float* __restrict__ A0, const float* __restrict__ W0,
    const float* __restrict__ A1, const float* __restrict__ W1,
    float* __restrict__ out, int steps, int kslice)
{
    // 2 bufs x (A 256x64 bf16 32KB + B 32KB) = 128 KB (gfx950 LDS = 160 KB)
    __shared__ __align__(16) unsigned char smem[131072];

    const int t    = threadIdx.x;
    const int lane = t & 63;
    const int wid  = t >> 6;          // 0..15
    const int bid  = blockIdx.x;
    const int ks    = bid & 15;       // K-slice (bid%8 -> XCD round-robin:
    const int ntile = bid >> 4;       //  slices ks, ks+8 share an XCD's L2)
    const int n0 = ntile * 256;
    const int wrow = (wid >> 2) * 64; // wave M offset
    const int wcol = (wid & 3) * 64;  // wave N offset
    const int lr = lane & 15;
    const int lk = lane >> 4;         // 0..3

    const float* As; const float* Ws; int koff;
    if (MODE == 0) {
        if (ks < 8) { As = A0; Ws = W0; koff = ks * kslice; }
        else        { As = A1; Ws = W1; koff = (ks - 8) * kslice; }
    } else { As = A0; Ws = W0; koff = ks * kslice; }

    // Staging: wave stages A rows [wid*16, +16) and B rows likewise.
    // lane -> sub-row lr8 = lane>>3 (+0/+8), 16B-bf16 dest chunk ch = lane&7.
    const int lr8   = lane >> 3;
    const int ch    = lane & 7;
    const int rbase = wid * 16;

    // Single staging set (8 float4 = 32 VGPR), statically indexed.
    float4 sa0, sa1, sa2, sa3, sb0, sb1, sb2, sb3;

#define ISSUE(step)                                                             \
    {                                                                           \
        const int kb = koff + (step) * 64 + ch * 8;                             \
        const float* ap = As + (size_t)(rbase + lr8) * HDIM + kb;               \
        const float* wp = Ws + (size_t)(n0 + rbase + lr8) * HDIM + kb;          \
        sa0 = *(const float4*)(ap);            sa1 = *(const float4*)(ap + 4);  \
        sa2 = *(const float4*)(ap + 8 * HDIM); sa3 = *(const float4*)(ap + 8 * HDIM + 4); \
        sb0 = *(const float4*)(wp);            sb1 = *(const float4*)(wp + 4);  \
        sb2 = *(const float4*)(wp + 8 * HDIM); sb3 = *(const float4*)(wp + 8 * HDIM + 4); \
    }

    // bf16 row = 64 elems = 128 B = 8 chunks of 16B; slot = ch ^ (row&7).
#define WRITEBUF(b)                                                             \
    {                                                                           \
        unsigned char* base = smem + (b) * 65536;                               \
        const int r0 = rbase + lr8, r1 = r0 + 8;                                \
        const int o0 = r0 * 128 + ((ch ^ (r0 & 7)) * 16);                       \
        const int o1 = r1 * 128 + ((ch ^ (r1 & 7)) * 16);                       \
        *(short8*)(base + o0)         = pack8(sa0, sa1);                        \
        *(short8*)(base + o1)         = pack8(sa2, sa3);                        \
        *(short8*)(base + 32768 + o0) = pack8(sb0, sb1);                        \
        *(short8*)(base + 32768 + o1) = pack8(sb2, sb3);                        \
    }

    f32x4 acc[4][4];
#pragma unroll
    for (int i = 0; i < 4; ++i)
#pragma unroll
        for (int j = 0; j < 4; ++j) acc[i][j] = (f32x4){0.f, 0.f, 0.f, 0.f};

    auto compute = [&](int b) {
        const unsigned char* base = smem + b * 65536;
#pragma unroll
        for (int s = 0; s < 2; ++s) {          // two K=32 sub-steps of BK=64
            short8 af[4], bv[4];
#pragma unroll
            for (int mr = 0; mr < 4; ++mr) {
                const int r = wrow + mr * 16 + lr;
                af[mr] = *(const short8*)(base + r * 128 + (((s * 4 + lk) ^ (r & 7)) * 16));
            }
#pragma unroll
            for (int nr = 0; nr < 4; ++nr) {
                const int r = wcol + nr * 16 + lr;
                bv[nr] = *(const short8*)(base + 32768 + r * 128 + (((s * 4 + lk) ^ (r & 7)) * 16));
            }
#pragma unroll
            for (int mr = 0; mr < 4; ++mr)
#pragma unroll
                for (int nr = 0; nr < 4; ++nr)
                    acc[mr][nr] = __builtin_amdgcn_mfma_f32_16x16x32_bf16(
                        af[mr], bv[nr], acc[mr][nr], 0, 0, 0);
        }
    };

    // Prologue: stage step0 -> buf0; issue step1 (stays in flight).
    ISSUE(0);
    asm volatile("s_waitcnt vmcnt(0)" ::: "memory");
    WRITEBUF(0);
    ISSUE(1);
    asm volatile("s_waitcnt lgkmcnt(0)" ::: "memory");
    __builtin_amdgcn_s_barrier();

    // Steady state: iter t computes buf(t&1); S holds step t+1 in flight
    // (issued one full iteration earlier -> latency window = whole step).
    for (int tt = 0; tt < steps; ++tt) {
        compute(tt & 1);
        if (tt + 1 < steps) {
            asm volatile("s_waitcnt vmcnt(0)" ::: "memory");  // S arrived
            WRITEBUF((tt + 1) & 1);
            if (tt + 2 < steps) ISSUE(tt + 2);                // refill S early
            asm volatile("s_waitcnt lgkmcnt(0)" ::: "memory");
        }
        __builtin_amdgcn_s_barrier();
    }
#undef ISSUE
#undef WRITEBUF

    // Epilogue: atomic accumulate partial tile (out zeroed by memset).
    // C/D layout: col = lane&15, row = (lane>>4)*4 + reg.
#pragma unroll
    for (int mr = 0; mr < 4; ++mr)
#pragma unroll
        for (int nr = 0; nr < 4; ++nr) {
            const int n = n0 + wcol + nr * 16 + lr;
#pragma unroll
            for (int e = 0; e < 4; ++e) {
                const int m = wrow + mr * 16 + lk * 4 + e;
                atomicAdd(&out[(size_t)m * HDIM + n], acc[mr][nr][e]);
            }
        }
}

// hn = tanh(hn_acc + b_ih + b_hh), elementwise over [256][4096].
__global__ __launch_bounds__(256) void finish_hn(
    float* __restrict__ hn, const float* __restrict__ b_ih,
    const float* __restrict__ b_hh)
{
    const int idx = blockIdx.x * 256 + threadIdx.x;   // f32x4 index
    const int col = (idx & 1023) * 4;
    f32x4 v  = *((const f32x4*)hn + idx);
    f32x4 bi = *(const f32x4*)(b_ih + col);
    f32x4 bh = *(const f32x4*)(b_hh + col);
#pragma unroll
    for (int j = 0; j < 4; ++j) v[j] = tanhf(v[j] + bi[j] + bh[j]);
    *((f32x4*)hn + idx) = v;
}

// probs = softmax(logits + b_lin) per row, in place.
__global__ __launch_bounds__(256) void softmax_bias(
    float* __restrict__ p, const float* __restrict__ bl)
{
    const int row = blockIdx.x;
    float* rp = p + (size_t)row * HDIM;
    const int t = threadIdx.x;

    f32x4 v[4];
#pragma unroll
    for (int i = 0; i < 4; ++i) {
        const int c = t + i * 256;
        v[i] = *(const f32x4*)(rp + c * 4);
        f32x4 b = *(const f32x4*)(bl + c * 4);
        v[i] += b;
    }

    float mx = -1e30f;
#pragma unroll
    for (int i = 0; i < 4; ++i)
#pragma unroll
        for (int j = 0; j < 4; ++j) mx = fmaxf(mx, v[i][j]);
#pragma unroll
    for (int off = 32; off; off >>= 1) mx = fmaxf(mx, __shfl_xor(mx, off));

    __shared__ float red[4];
    if ((t & 63) == 0) red[t >> 6] = mx;
    __syncthreads();
    mx = fmaxf(fmaxf(red[0], red[1]), fmaxf(red[2], red[3]));

    float sum = 0.f;
#pragma unroll
    for (int i = 0; i < 4; ++i)
#pragma unroll
        for (int j = 0; j < 4; ++j) {
            float e = __expf(v[i][j] - mx);
            v[i][j] = e;
            sum += e;
        }
#pragma unroll
    for (int off = 32; off; off >>= 1) sum += __shfl_xor(sum, off);

    __syncthreads();
    if ((t & 63) == 0) red[t >> 6] = sum;
    __syncthreads();
    sum = (red[0] + red[1]) + (red[2] + red[3]);

    const float inv = 1.f / sum;
#pragma unroll
    for (int i = 0; i < 4; ++i) {
        f32x4 o = v[i];
#pragma unroll
        for (int j = 0; j < 4; ++j) o[j] *= inv;
        *(f32x4*)(rp + (t + i * 256) * 4) = o;
    }
}

extern "C" void kernel_launch(void* const* d_in, const int* in_sizes, int n_in,
                              void* d_out, int out_size, void* d_ws, size_t ws_size,
                              hipStream_t stream) {
    const float* x     = (const float*)d_in[0];   // [256,4096]
    const float* h0    = (const float*)d_in[1];   // [1,256,4096]
    const float* w_ih  = (const float*)d_in[2];   // [4096,4096]
    const float* b_ih  = (const float*)d_in[3];
    const float* w_hh  = (const float*)d_in[4];
    const float* b_hh  = (const float*)d_in[5];
    const float* w_lin = (const float*)d_in[6];
    const float* b_lin = (const float*)d_in[7];

    float* probs = (float*)d_out;                 // logits acc, then probs
    float* hn    = (float*)d_out + 256 * HDIM;    // hn acc, then tanh'd

    // Zero both accumulation regions (d_out is 0xAA-poisoned each launch).
    hipMemsetAsync(d_out, 0, (size_t)2 * 256 * HDIM * sizeof(float), stream);

    // hn_acc += x@w_ih^T (ks 0..7) + h@w_hh^T (ks 8..15); 8 steps of BK=64
    rnn_gemm<0><<<256, 1024, 0, stream>>>(x, w_ih, h0, w_hh, hn,
                                          /*steps=*/8, /*kslice=*/512);
    finish_hn<<<1024, 256, 0, stream>>>(hn, b_ih, b_hh);
    // logits_acc += hn@w_lin^T; K=4096 in 16 slices of 256; 4 steps
    rnn_gemm<1><<<256, 1024, 0, stream>>>(hn, w_lin, nullptr, nullptr, probs,
                                          /*steps=*/4, /*kslice=*/256);
    softmax_bias<<<256, 256, 0, stream>>>(probs, b_lin);
}

// Round 7
// 270.041 us; speedup vs baseline: 1.2313x; 1.2313x over previous
//
#include <hip/hip_runtime.h>
#include <hip/hip_bf16.h>
#include <cstdint>

// B=256, I=H=O=4096 single-step Elman RNN + linear + softmax.
// out[0..1048576) = probs (fp32), out[1048576..2097152) = hn (fp32).
//
// R7: kill the atomicAdd epilogue (R5/R6's hidden dominant cost — MODE0 and
// MODE1 both ~108us despite 2x mainloop work = epilogue-bound; 16-way
// same-cacheline RMW serialization).
//  - Each block stores its 256x256 fp32 partial to d_ws, plain coalesced
//    stores (64 MB, no contention).
//  - red_tanh: sum nsplit partials + b_ih + b_hh + tanh -> hn.
//  - red_softmax: sum nsplit partials + b_lin + row softmax -> probs.
//  - No memset, no atomics. ws reuse GEMM1->red1->GEMM2 is stream-ordered.
//  - nsplit adapts to ws_size (16 preferred); constant per process.
// Mainloop unchanged from R6 (256x256 tile, BK=64 bf16 LDS dbuf, T14
// issue-early/write-late, XOR swizzle; FETCH was compulsory at 74.6 MB).

using short8 = __attribute__((ext_vector_type(8))) short;
using f32x4  = __attribute__((ext_vector_type(4))) float;

#define HDIM 4096

__device__ __forceinline__ short bfbits(float f) {
    __bf16 b = (__bf16)f;
    return __builtin_bit_cast(short, b);
}
__device__ __forceinline__ short8 pack8(const float4& a, const float4& b) {
    short8 r;
    r[0] = bfbits(a.x); r[1] = bfbits(a.y); r[2] = bfbits(a.z); r[3] = bfbits(a.w);
    r[4] = bfbits(b.x); r[5] = bfbits(b.y); r[6] = bfbits(b.z); r[7] = bfbits(b.w);
    return r;
}

// One K-slice partial of A[256 x K] @ W^T -> P[ks][256][4096] (cols n0..n0+255).
// MODE 0: slices 0..h-1 -> (A0,W0), h..2h-1 -> (A1,W1), h = nsplit/2.
// MODE 1: slices 0..nsplit-1 -> contiguous K pieces of (A0,W0).
// Block: 1024 thr = 16 waves (4M x 4N), wave-tile 64x64, BK=64 bf16 LDS.
template<int MODE>
__global__ __launch_bounds__(1024) void rnn_gemm(
    const float* __restrict__ A0, const float* __restrict__ W0,
    const float* __restrict__ A1, const float* __restrict__ W1,
    float* __restrict__ P, int steps, int kslice, int nsplit)
{
    // 2 bufs x (A 256x64 bf16 32KB + B 32KB) = 128 KB
    __shared__ __align__(16) unsigned char smem[131072];

    const int t    = threadIdx.x;
    const int lane = t & 63;
    const int wid  = t >> 6;          // 0..15
    const int bid  = blockIdx.x;
    const int ks    = bid % nsplit;   // bid%8==ks%8 -> all ntiles of slice ks
    const int ntile = bid / nsplit;   //   land on one XCD (A-slice L2-local)
    const int n0 = ntile * 256;
    const int wrow = (wid >> 2) * 64; // wave M offset
    const int wcol = (wid & 3) * 64;  // wave N offset
    const int lr = lane & 15;
    const int lk = lane >> 4;         // 0..3

    const float* As; const float* Ws; int koff;
    if (MODE == 0) {
        const int half = nsplit >> 1;
        if (ks < half) { As = A0; Ws = W0; koff = ks * kslice; }
        else           { As = A1; Ws = W1; koff = (ks - half) * kslice; }
    } else { As = A0; Ws = W0; koff = ks * kslice; }

    // Staging: wave stages A rows [wid*16,+16) and B rows likewise.
    const int lr8   = lane >> 3;      // sub-row (+0/+8)
    const int ch    = lane & 7;       // 16B-bf16 dest chunk
    const int rbase = wid * 16;

    // Single staging set (8 float4), statically indexed (rule #20).
    float4 sa0, sa1, sa2, sa3, sb0, sb1, sb2, sb3;

#define ISSUE(step)                                                             \
    {                                                                           \
        const int kb = koff + (step) * 64 + ch * 8;                             \
        const float* ap = As + (size_t)(rbase + lr8) * HDIM + kb;               \
        const float* wp = Ws + (size_t)(n0 + rbase + lr8) * HDIM + kb;          \
        sa0 = *(const float4*)(ap);            sa1 = *(const float4*)(ap + 4);  \
        sa2 = *(const float4*)(ap + 8 * HDIM); sa3 = *(const float4*)(ap + 8 * HDIM + 4); \
        sb0 = *(const float4*)(wp);            sb1 = *(const float4*)(wp + 4);  \
        sb2 = *(const float4*)(wp + 8 * HDIM); sb3 = *(const float4*)(wp + 8 * HDIM + 4); \
    }

    // bf16 row = 64 elems = 128 B = 8 chunks of 16B; slot = ch ^ (row&7),
    // applied identically on write and read (both-sides rule #21).
#define WRITEBUF(b)                                                             \
    {                                                                           \
        unsigned char* base = smem + (b) * 65536;                               \
        const int r0 = rbase + lr8, r1 = r0 + 8;                                \
        const int o0 = r0 * 128 + ((ch ^ (r0 & 7)) * 16);                       \
        const int o1 = r1 * 128 + ((ch ^ (r1 & 7)) * 16);                       \
        *(short8*)(base + o0)         = pack8(sa0, sa1);                        \
        *(short8*)(base + o1)         = pack8(sa2, sa3);                        \
        *(short8*)(base + 32768 + o0) = pack8(sb0, sb1);                        \
        *(short8*)(base + 32768 + o1) = pack8(sb2, sb3);                        \
    }

    f32x4 acc[4][4];
#pragma unroll
    for (int i = 0; i < 4; ++i)
#pragma unroll
        for (int j = 0; j < 4; ++j) acc[i][j] = (f32x4){0.f, 0.f, 0.f, 0.f};

    auto compute = [&](int b) {
        const unsigned char* base = smem + b * 65536;
#pragma unroll
        for (int s = 0; s < 2; ++s) {          // two K=32 sub-steps of BK=64
            short8 af[4], bv[4];
#pragma unroll
            for (int mr = 0; mr < 4; ++mr) {
                const int r = wrow + mr * 16 + lr;
                af[mr] = *(const short8*)(base + r * 128 + (((s * 4 + lk) ^ (r & 7)) * 16));
            }
#pragma unroll
            for (int nr = 0; nr < 4; ++nr) {
                const int r = wcol + nr * 16 + lr;
                bv[nr] = *(const short8*)(base + 32768 + r * 128 + (((s * 4 + lk) ^ (r & 7)) * 16));
            }
#pragma unroll
            for (int mr = 0; mr < 4; ++mr)
#pragma unroll
                for (int nr = 0; nr < 4; ++nr)
                    acc[mr][nr] = __builtin_amdgcn_mfma_f32_16x16x32_bf16(
                        af[mr], bv[nr], acc[mr][nr], 0, 0, 0);
        }
    };

    // Prologue: stage step0 -> buf0; issue step1 (stays in flight).
    ISSUE(0);
    asm volatile("s_waitcnt vmcnt(0)" ::: "memory");
    WRITEBUF(0);
    ISSUE(1);
    asm volatile("s_waitcnt lgkmcnt(0)" ::: "memory");
    __builtin_amdgcn_s_barrier();

    // Steady state: iter t computes buf(t&1); staging set holds step t+1,
    // issued a full iteration earlier (latency window = whole step).
    for (int tt = 0; tt < steps; ++tt) {
        compute(tt & 1);
        if (tt + 1 < steps) {
            asm volatile("s_waitcnt vmcnt(0)" ::: "memory");
            WRITEBUF((tt + 1) & 1);
            if (tt + 2 < steps) ISSUE(tt + 2);
            asm volatile("s_waitcnt lgkmcnt(0)" ::: "memory");
        }
        __builtin_amdgcn_s_barrier();
    }
#undef ISSUE
#undef WRITEBUF

    // Epilogue: plain coalesced stores of the partial tile to ws slice ks.
    // C/D layout: col = lane&15, row = (lane>>4)*4 + reg.
    float* slice = P + (size_t)ks * (256 * HDIM);
#pragma unroll
    for (int mr = 0; mr < 4; ++mr)
#pragma unroll
        for (int nr = 0; nr < 4; ++nr) {
            const int n = n0 + wcol + nr * 16 + lr;
#pragma unroll
            for (int e = 0; e < 4; ++e) {
                const int m = wrow + mr * 16 + lk * 4 + e;
                slice[(size_t)m * HDIM + n] = acc[mr][nr][e];
            }
        }
}

// hn = tanh(sum_k P[k] + b_ih + b_hh), elementwise over [256][4096].
__global__ __launch_bounds__(256) void red_tanh(
    const float* __restrict__ P, const float* __restrict__ b_ih,
    const float* __restrict__ b_hh, float* __restrict__ hn, int nsplit)
{
    const int idx = blockIdx.x * 256 + threadIdx.x;   // f32x4 index
    const int col = (idx & 1023) * 4;
    f32x4 s0 = (f32x4){0.f, 0.f, 0.f, 0.f};
    f32x4 s1 = (f32x4){0.f, 0.f, 0.f, 0.f};
    for (int k = 0; k + 1 < nsplit; k += 2) {          // 2 chains for MLP
        s0 += *((const f32x4*)(P + (size_t)k * 1048576) + idx);
        s1 += *((const f32x4*)(P + (size_t)(k + 1) * 1048576) + idx);
    }
    if (nsplit & 1) s0 += *((const f32x4*)(P + (size_t)(nsplit - 1) * 1048576) + idx);
    f32x4 v  = s0 + s1;
    f32x4 bi = *(const f32x4*)(b_ih + col);
    f32x4 bh = *(const f32x4*)(b_hh + col);
#pragma unroll
    for (int j = 0; j < 4; ++j) v[j] = tanhf(v[j] + bi[j] + bh[j]);
    *((f32x4*)hn + idx) = v;
}

// probs = softmax(sum_k P[k] + b_lin) per row.
__global__ __launch_bounds__(256) void red_softmax(
    const float* __restrict__ P, const float* __restrict__ bl,
    float* __restrict__ probs, int nsplit)
{
    const int row = blockIdx.x;
    const int t = threadIdx.x;
    const float* rp = P + (size_t)row * HDIM;

    f32x4 v[4];
#pragma unroll
    for (int i = 0; i < 4; ++i) {
        const int c = (t + i * 256) * 4;               // col
        f32x4 s0 = (f32x4){0.f, 0.f, 0.f, 0.f};
        f32x4 s1 = (f32x4){0.f, 0.f, 0.f, 0.f};
        for (int k = 0; k + 1 < nsplit; k += 2) {
            s0 += *(const f32x4*)(rp + (size_t)k * 1048576 + c);
            s1 += *(const f32x4*)(rp + (size_t)(k + 1) * 1048576 + c);
        }
        if (nsplit & 1) s0 += *(const f32x4*)(rp + (size_t)(nsplit - 1) * 1048576 + c);
        f32x4 b = *(const f32x4*)(bl + c);
        v[i] = s0 + s1 + b;
    }

    float mx = -1e30f;
#pragma unroll
    for (int i = 0; i < 4; ++i)
#pragma unroll
        for (int j = 0; j < 4; ++j) mx = fmaxf(mx, v[i][j]);
#pragma unroll
    for (int off = 32; off; off >>= 1) mx = fmaxf(mx, __shfl_xor(mx, off));

    __shared__ float red[4];
    if ((t & 63) == 0) red[t >> 6] = mx;
    __syncthreads();
    mx = fmaxf(fmaxf(red[0], red[1]), fmaxf(red[2], red[3]));

    float sum = 0.f;
#pragma unroll
    for (int i = 0; i < 4; ++i)
#pragma unroll
        for (int j = 0; j < 4; ++j) {
            float e = __expf(v[i][j] - mx);
            v[i][j] = e;
            sum += e;
        }
#pragma unroll
    for (int off = 32; off; off >>= 1) sum += __shfl_xor(sum, off);

    __syncthreads();
    if ((t & 63) == 0) red[t >> 6] = sum;
    __syncthreads();
    sum = (red[0] + red[1]) + (red[2] + red[3]);

    const float inv = 1.f / sum;
    float* op = probs + (size_t)row * HDIM;
#pragma unroll
    for (int i = 0; i < 4; ++i) {
        f32x4 o = v[i];
#pragma unroll
        for (int j = 0; j < 4; ++j) o[j] *= inv;
        *(f32x4*)(op + (t + i * 256) * 4) = o;
    }
}

extern "C" void kernel_launch(void* const* d_in, const int* in_sizes, int n_in,
                              void* d_out, int out_size, void* d_ws, size_t ws_size,
                              hipStream_t stream) {
    const float* x     = (const float*)d_in[0];   // [256,4096]
    const float* h0    = (const float*)d_in[1];   // [1,256,4096]
    const float* w_ih  = (const float*)d_in[2];   // [4096,4096]
    const float* b_ih  = (const float*)d_in[3];
    const float* w_hh  = (const float*)d_in[4];
    const float* b_hh  = (const float*)d_in[5];
    const float* w_lin = (const float*)d_in[6];
    const float* b_lin = (const float*)d_in[7];

    float* probs = (float*)d_out;
    float* hn    = (float*)d_out + 256 * HDIM;
    float* P     = (float*)d_ws;                  // nsplit x 4 MB partials

    // nsplit adapts to ws capacity (constant across calls -> capture-safe).
    const int nsplit = ws_size >= ((size_t)64 << 20) ? 16
                     : ws_size >= ((size_t)32 << 20) ? 8
                     : ws_size >= ((size_t)16 << 20) ? 4 : 2;
    const int ks0 = 8192 / nsplit;                // MODE0 per-slice K
    const int ks1 = 4096 / nsplit;                // MODE1 per-slice K

    // P[ks] = partial of x@w_ih^T / h@w_hh^T  (slices split x|h)
    rnn_gemm<0><<<16 * nsplit, 1024, 0, stream>>>(x, w_ih, h0, w_hh, P,
                                                  ks0 / 64, ks0, nsplit);
    // hn = tanh(sum P + b_ih + b_hh)
    red_tanh<<<1024, 256, 0, stream>>>(P, b_ih, b_hh, hn, nsplit);
    // P[ks] = partial of hn@w_lin^T   (ws reuse is stream-ordered)
    rnn_gemm<1><<<16 * nsplit, 1024, 0, stream>>>(hn, w_lin, nullptr, nullptr, P,
                                                  ks1 / 64, ks1, nsplit);
    // probs = softmax(sum P + b_lin)
    red_softmax<<<256, 256, 0, stream>>>(P, b_lin, probs, nsplit);
}